// Round 3
// baseline (621.602 us; speedup 1.0000x reference)
//
#include <hip/hip_runtime.h>
#include <hip/hip_bf16.h>

// Problem constants (from reference): B=2048, S=200, H=128, nh=2, L=7, d=64
#define SEQ 200
#define HID 128
#define NLVL 7

__device__ __forceinline__ float bf_lo(unsigned u) { return __uint_as_float(u << 16); }
__device__ __forceinline__ float bf_hi(unsigned u) { return __uint_as_float(u & 0xffff0000u); }

__device__ __forceinline__ unsigned short bf_bits(float f) {
    __hip_bfloat16 h = __float2bfloat16(f);  // RNE
    return *reinterpret_cast<unsigned short*>(&h);
}
__device__ __forceinline__ unsigned pack_bf(float a, float b) {
    return (unsigned)bf_bits(a) | ((unsigned)bf_bits(b) << 16);
}

// Linear row: dot(x[0..127], W[c,:]) + bias[c]; W row-major [H][H]
template<bool FP32>
__device__ __forceinline__ float lin_row(const float* x, const void* W, const void* bias, int c) {
    float acc;
    if constexpr (FP32) {
        const float* wrow = (const float*)W + c * HID;
        acc = ((const float*)bias)[c];
        #pragma unroll 8
        for (int k = 0; k < HID; ++k) acc += x[k] * wrow[k];
    } else {
        const unsigned* wrow = (const unsigned*)W + c * (HID / 2);
        unsigned ub = ((const unsigned*)bias)[c >> 1];
        acc = (c & 1) ? bf_hi(ub) : bf_lo(ub);
        #pragma unroll 8
        for (int k = 0; k < HID / 2; ++k) {
            unsigned u = wrow[k];
            acc += x[2 * k] * bf_lo(u) + x[2 * k + 1] * bf_hi(u);
        }
    }
    return acc;
}

template<bool FP32>
__device__ __forceinline__ float w_elem(const void* W, int r, int c) {
    if constexpr (FP32) return ((const float*)W)[r * HID + c];
    else {
        unsigned u = ((const unsigned*)W)[(r * HID + c) >> 1];
        return (c & 1) ? bf_hi(u) : bf_lo(u);
    }
}
template<bool FP32>
__device__ __forceinline__ float b_elem(const void* bias, int r) {
    if constexpr (FP32) return ((const float*)bias)[r];
    else {
        unsigned u = ((const unsigned*)bias)[r >> 1];
        return (r & 1) ? bf_hi(u) : bf_lo(u);
    }
}

template<bool FP32>
__global__ __launch_bounds__(256) void mixer_kernel(
    const int* __restrict__ item_seq,     // [B,S] int32
    const void* __restrict__ emb_v,       // [B,S,H] fp32 (detected) or bf16
    const int* __restrict__ seq_len,      // [B]
    const void* __restrict__ Wlq_v,       // [H,H]
    const void* __restrict__ blq_v,       // [H]
    const void* __restrict__ Wq_v,
    const void* __restrict__ bq_v,
    const void* __restrict__ Wk_v,
    const void* __restrict__ bk_v,
    void* __restrict__ out_v)             // [B,H], dtype matches input family
{
    // ---- dtype detector: (word >> 7) & 0xff. For packed-bf16 data this is the
    // exponent of an N(0,1) bf16 (in [118,130] w.p. ~0.999); for fp32 data it is
    // uniform mantissa bits (in range w.p. ~0.05). Uniform across threads/blocks.
    {
        const unsigned* eu = (const unsigned*)emb_v;
        int cnt = 0;
        #pragma unroll
        for (int w = 0; w < 32; ++w) {
            unsigned e = (eu[w] >> 7) & 0xff;
            cnt += (e >= 118 && e <= 130) ? 1 : 0;
        }
        bool data_is_fp32 = (cnt < 16);
        if (data_is_fp32 != FP32) return;  // wrong-dtype instantiation: no-op
    }

    const int b   = blockIdx.x;
    const int tid = threadIdx.x;

    // LDS layout (total 80,280 B -> 2 blocks/CU of 160 KiB)
    __shared__ unsigned s_embu[SEQ * 65];  // emb rows as packed bf16, stride 65 (conflict-free strided reads)
    __shared__ float    s_qk[28 * 128];    // folded q @ Wk vectors
    __shared__ float    s_qb[28];          // folded q . bk scalars
    __shared__ float    s_tmp[2800];       // A: lvl[0..895]|queries[896..1791]; B: q[0..895]; C: scores[14][200]
    __shared__ float    s_A[400];          // exp of LP-pooled, masked [2][200]
    __shared__ float    s_red[256];
    __shared__ float    s_inv[2];

    // ---- stage 0: global -> LDS emb slab (packed bf16 either way) ----
    if constexpr (FP32) {
        const float4* src = (const float4*)((const float*)emb_v + (size_t)b * SEQ * HID);
        for (int i = tid; i < SEQ * 32; i += 256) {   // 6400 x 16B
            int row = i >> 5, j = i & 31;
            float4 v = src[i];
            unsigned* dst = s_embu + row * 65 + 2 * j;
            dst[0] = pack_bf(v.x, v.y);
            dst[1] = pack_bf(v.z, v.w);
        }
    } else {
        const uint4* src = (const uint4*)((const unsigned*)emb_v + (size_t)b * (SEQ * HID / 2));
        for (int i = tid; i < SEQ * 16; i += 256) {   // 3200 x 16B
            int row = i >> 4, col4 = (i & 15) * 4;
            uint4 v = src[i];
            unsigned* dst = s_embu + row * 65 + col4;
            dst[0] = v.x; dst[1] = v.y; dst[2] = v.z; dst[3] = v.w;
        }
    }
    __syncthreads();

    // ---- stage 1: multi-level gather + cumsum -> level_emb [7][128] in s_tmp[0..895] ----
    const int len = seq_len[b];
    if (tid < HID) {
        const int c = tid;
        float acc = 0.f;
        for (int j = 0; j < NLVL; ++j) {
            int idx = len - (j + 1);
            if (idx < 0) idx = SEQ - 1;  // torch clamp(-1) + wrap
            float e;
            if constexpr (FP32) {
                e = ((const float*)emb_v)[(size_t)b * SEQ * HID + (size_t)idx * HID + c];
            } else {
                unsigned u = s_embu[idx * 65 + (c >> 1)];
                e = (c & 1) ? bf_hi(u) : bf_lo(u);
            }
            acc += e;
            s_tmp[j * HID + c] = acc;
        }
    }
    __syncthreads();

    // ---- stage 2: queries = level_emb @ W_lq^T + b_lq -> s_tmp[896..1791] ----
    for (int t = tid; t < NLVL * HID; t += 256) {
        int l = t >> 7, c = t & 127;
        s_tmp[896 + t] = lin_row<FP32>(s_tmp + l * HID, Wlq_v, blq_v, c);
    }
    __syncthreads();

    // ---- stage 3: q = queries @ Wq^T + bq -> s_tmp[0..895] ----
    for (int t = tid; t < NLVL * HID; t += 256) {
        int l = t >> 7, c = t & 127;
        s_tmp[t] = lin_row<FP32>(s_tmp + 896 + l * HID, Wq_v, bq_v, c);
    }
    __syncthreads();

    // ---- stage 4: fold Wk into q. q flat viewed [14][64]; qrow = hl*2+par ----
    for (int o = tid; o < 28 * 128; o += 256) {
        int qrow = o >> 7, c = o & 127;
        int hl = qrow >> 1, par = qrow & 1;
        const float* qv = s_tmp + hl * 64;
        float acc = 0.f;
        #pragma unroll 8
        for (int d2 = 0; d2 < 64; ++d2)
            acc += qv[d2] * w_elem<FP32>(Wk_v, par * 64 + d2, c);
        s_qk[qrow * 128 + c] = acc;
    }
    if (tid < 28) {
        int hl = tid >> 1, par = tid & 1;
        float acc = 0.f;
        for (int d2 = 0; d2 < 64; ++d2)
            acc += s_tmp[hl * 64 + d2] * b_elem<FP32>(bk_v, par * 64 + d2);
        s_qb[tid] = acc;
    }
    __syncthreads();

    // ---- stage 5: scores + sigmoid -> s_tmp[14][200] ----
    for (int o = tid; o < 700; o += 256) {
        int hl = o / 50, g = o % 50;
        int h = (hl >= 7) ? 1 : 0;
        int rA = h * 100 + g, rB = rA + 50;
        int q0 = hl * 2, q1 = q0 + 1;
        const unsigned* eA = s_embu + rA * 65;
        const unsigned* eB = s_embu + rB * 65;
        const float* k0 = s_qk + q0 * 128;
        const float* k1 = s_qk + q1 * 128;
        float a0 = 0.f, a1 = 0.f, c0a = 0.f, c1a = 0.f;
        #pragma unroll 4
        for (int kk = 0; kk < 64; ++kk) {
            unsigned uA = eA[kk], uB = eB[kk];
            float2 w0 = *(const float2*)(k0 + 2 * kk);
            float2 w1 = *(const float2*)(k1 + 2 * kk);
            float alo = bf_lo(uA), ahi = bf_hi(uA);
            float blo = bf_lo(uB), bhi = bf_hi(uB);
            a0  += alo * w0.x + ahi * w0.y;
            a1  += alo * w1.x + ahi * w1.y;
            c0a += blo * w0.x + bhi * w0.y;
            c1a += blo * w1.x + bhi * w1.y;
        }
        float qb0 = s_qb[q0], qb1 = s_qb[q1];
        float* row = s_tmp + hl * 200;
        row[2 * g]       = 1.f / (1.f + __expf(-(a0  + qb0)));
        row[2 * g + 1]   = 1.f / (1.f + __expf(-(a1  + qb1)));
        row[2 * g + 100] = 1.f / (1.f + __expf(-(c0a + qb0)));
        row[2 * g + 101] = 1.f / (1.f + __expf(-(c1a + qb1)));
    }
    __syncthreads();

    // ---- stage 6: softmax over s2 per (h,l) row; inputs in (0,1), skip max-sub ----
    const int wave = tid >> 6, lane = tid & 63;
    for (int r = wave; r < 14; r += 4) {
        float* row = s_tmp + r * 200;
        float e0 = __expf(row[lane]);
        float e1 = __expf(row[lane + 64]);
        float e2 = __expf(row[lane + 128]);
        float e3 = (lane + 192 < 200) ? __expf(row[lane + 192]) : 0.f;
        float sum = e0 + e1 + e2 + e3;
        #pragma unroll
        for (int m = 1; m < 64; m <<= 1) sum += __shfl_xor(sum, m, 64);
        float inv = 1.f / sum;
        row[lane]       = e0 * inv;
        row[lane + 64]  = e1 * inv;
        row[lane + 128] = e2 * inv;
        if (lane + 192 < 200) row[lane + 192] = e3 * inv;
    }
    __syncthreads();

    // ---- stage 7: LP-pool (p=4) + mask + exp (2nd softmax numerator) ----
    for (int o = tid; o < 2 * SEQ; o += 256) {
        int h = o / SEQ, s2 = o % SEQ;
        float ssum = 0.f;
        #pragma unroll
        for (int l = 0; l < NLVL; ++l) {
            float v = s_tmp[(h * NLVL + l) * 200 + s2];
            float v2 = v * v;
            ssum += v2 * v2;
        }
        float A = sqrtf(sqrtf(ssum));
        int m = item_seq[(size_t)b * SEQ + s2];
        s_A[o] = (m > 0) ? __expf(A) : 0.f;
    }
    __syncthreads();

    // ---- stage 8: 2nd softmax denominators per head ----
    if (wave < 2) {
        const float* row = s_A + wave * SEQ;
        float sum = row[lane] + row[lane + 64] + row[lane + 128]
                  + ((lane + 192 < 200) ? row[lane + 192] : 0.f);
        #pragma unroll
        for (int m = 1; m < 64; m <<= 1) sum += __shfl_xor(sum, m, 64);
        if (lane == 0) s_inv[wave] = 1.f / sum;
    }
    __syncthreads();

    // ---- stage 9: out[c] = (1/den) * sum_s2 w[h(c)][s2] * emb[s2][c] ----
    {
        int c = tid & 127, halfb = tid >> 7;
        int h = c >> 6;
        const float* wv = s_A + h * SEQ + halfb * 100;
        float acc = 0.f;
        #pragma unroll 4
        for (int s2 = 0; s2 < 100; ++s2) {
            unsigned u = s_embu[(halfb * 100 + s2) * 65 + (c >> 1)];
            float e = (c & 1) ? bf_hi(u) : bf_lo(u);
            acc += wv[s2] * e;
        }
        s_red[tid] = acc;
    }
    __syncthreads();
    if (tid < HID) {
        int c = tid, h = c >> 6;
        float tot = (s_red[c] + s_red[c + 128]) * s_inv[h];
        // Output dtype matches the detected input family.
        if constexpr (FP32) {
            ((float*)out_v)[(size_t)b * HID + c] = tot;
        } else {
            ((__hip_bfloat16*)out_v)[(size_t)b * HID + c] = __float2bfloat16(tot);
        }
    }
}

extern "C" void kernel_launch(void* const* d_in, const int* in_sizes, int n_in,
                              void* d_out, int out_size, void* d_ws, size_t ws_size,
                              hipStream_t stream) {
    const int* item_seq = (const int*)d_in[0];
    const void* emb     = d_in[1];
    const int* seq_len  = (const int*)d_in[2];
    const void* Wlq     = d_in[3];
    const void* blq     = d_in[4];
    const void* Wq      = d_in[5];
    const void* bq      = d_in[6];
    const void* Wk      = d_in[7];
    const void* bk      = d_in[8];

    const int B = in_sizes[2];  // 2048

    // Launch both dtype interpretations; each block self-detects and the
    // mismatched instantiation exits immediately (~µs). Exactly one writes out.
    mixer_kernel<false><<<B, 256, 0, stream>>>(item_seq, emb, seq_len, Wlq, blq, Wq, bq, Wk, bk, d_out);
    mixer_kernel<true ><<<B, 256, 0, stream>>>(item_seq, emb, seq_len, Wlq, blq, Wq, bq, Wk, bk, d_out);
}

// Round 4
// 452.961 us; speedup vs baseline: 1.3723x; 1.3723x over previous
//
#include <hip/hip_runtime.h>
#include <hip/hip_bf16.h>

// B=2048, S=200, H=128, nh=2, L=7, d=64. Inputs/outputs fp32 (verified round 3).
#define SEQ 200
#define HID 128
#define NLVL 7
#define ESTR 66  // LDS emb row stride (uints); even => 8B-aligned rows, 2-way bank alias (free)

// ws word offsets
#define WS_M    0         // M[4][128][128]: M[g][c][j] at g*16384 + c*128 + j
#define WS_BF   65536     // Bf[4][128]
#define WS_VB   66048     // vb[4][128]
#define WS_CB   66560     // cb[4]
#define WS_WC   66564     // Wcomb[128][128]
#define WS_BC   82948     // bcomb[128]
#define WS_WORDS 83076

__device__ __forceinline__ float bf_lo(unsigned u) { return __uint_as_float(u << 16); }
__device__ __forceinline__ float bf_hi(unsigned u) { return __uint_as_float(u & 0xffff0000u); }
__device__ __forceinline__ unsigned short bf_bits(float f) {
    __hip_bfloat16 h = __float2bfloat16(f);
    return *reinterpret_cast<unsigned short*>(&h);
}
__device__ __forceinline__ unsigned pack_bf(float a, float b) {
    return (unsigned)bf_bits(a) | ((unsigned)bf_bits(b) << 16);
}

// ---- precompute 0: Wcomb = Wq @ Wlq, bcomb = Wq @ b_lq + bq ----
__global__ __launch_bounds__(256) void precomp0(
    const float* __restrict__ Wlq, const float* __restrict__ blq,
    const float* __restrict__ Wq,  const float* __restrict__ bq,
    float* __restrict__ ws)
{
    int id = blockIdx.x * 256 + threadIdx.x;  // [0, 16384)
    int r = id >> 7, j = id & 127;
    float acc = 0.f;
    #pragma unroll 8
    for (int c = 0; c < 128; ++c) acc += Wq[r * 128 + c] * Wlq[c * 128 + j];
    ws[WS_WC + id] = acc;
    if (id < 128) {
        float b = bq[id];
        #pragma unroll 8
        for (int c = 0; c < 128; ++c) b += Wq[id * 128 + c] * blq[c];
        ws[WS_BC + id] = b;
    }
}

// ---- precompute 1: M[g][c][j] = sum_d Wcomb[(u*64+d)][j] * Wk[(par*64+d)][c], g=u*2+par; Bf, vb, cb ----
__global__ __launch_bounds__(256) void precomp1(
    const float* __restrict__ Wk, const float* __restrict__ bk, float* __restrict__ ws)
{
    int gid = blockIdx.x * 256 + threadIdx.x;
    if (gid < 65536) {
        int j = gid & 127, c = (gid >> 7) & 127, g = gid >> 14;
        int u = g >> 1, par = g & 1;
        const float* wc = ws + WS_WC + u * 64 * 128 + j;
        const float* wk = Wk + par * 64 * 128 + c;
        float acc = 0.f;
        #pragma unroll 8
        for (int d = 0; d < 64; ++d) acc += wc[d * 128] * wk[d * 128];
        ws[WS_M + gid] = acc;
    } else if (gid < 66048) {
        int t = gid - 65536, c = t & 127, g = t >> 7;
        int u = g >> 1, par = g & 1;
        float acc = 0.f;
        #pragma unroll 8
        for (int d = 0; d < 64; ++d)
            acc += ws[WS_BC + u * 64 + d] * Wk[(par * 64 + d) * 128 + c];
        ws[WS_BF + t] = acc;
    } else if (gid < 66560) {
        int t = gid - 66048, j = t & 127, g = t >> 7;
        int u = g >> 1, par = g & 1;
        float acc = 0.f;
        #pragma unroll 8
        for (int d = 0; d < 64; ++d)
            acc += ws[WS_WC + (u * 64 + d) * 128 + j] * bk[par * 64 + d];
        ws[WS_VB + t] = acc;
    } else if (gid < 66564) {
        int g = gid - 66560, u = g >> 1, par = g & 1;
        float acc = 0.f;
        for (int d = 0; d < 64; ++d)
            acc += ws[WS_BC + u * 64 + d] * bk[par * 64 + d];
        ws[WS_CB + g] = acc;
    }
}

// ---- main kernel: one block per batch, 512 threads ----
__global__ __launch_bounds__(512, 4) void mixer_main(
    const int* __restrict__ item_seq,
    const float* __restrict__ emb,
    const int* __restrict__ seq_len,
    const float* __restrict__ ws,
    float* __restrict__ out)
{
    const int b   = blockIdx.x;
    const int tid = threadIdx.x;

    __shared__ __align__(16) unsigned s_embu[SEQ * ESTR];  // 52800 B, packed bf16
    __shared__ __align__(16) float    s_pool1[28 * 128];   // qk; later partial sums  (14336 B)
    __shared__ float                  s_qb[28];
    __shared__ __align__(16) float    s_pool2[2800];       // lvl [7][128] then scores [14][200] (11200 B)
    __shared__ float                  s_A[2 * SEQ];        // 1600 B
    __shared__ float                  s_inv[2];
    // total 80,056 B -> 2 blocks/CU

    // ---- stage 0: emb -> LDS packed bf16 (coalesced float4) ----
    {
        const float4* src = (const float4*)(emb + (size_t)b * SEQ * HID);
        for (int i = tid; i < SEQ * 32; i += 512) {
            int row = i >> 5, j = i & 31;
            float4 v = src[i];
            unsigned* dst = s_embu + row * ESTR + 2 * j;
            dst[0] = pack_bf(v.x, v.y);
            dst[1] = pack_bf(v.z, v.w);
        }
    }
    // ---- stage 1: level gather + cumsum (fp32 from global) -> lvl in s_pool2[0..895] ----
    if (tid < HID) {
        const int len = seq_len[b];
        const int c = tid;
        float e[NLVL];
        #pragma unroll
        for (int j = 0; j < NLVL; ++j) {
            int idx = len - (j + 1);
            if (idx < 0) idx = SEQ - 1;  // torch clamp(-1) + wrap
            e[j] = emb[(size_t)b * SEQ * HID + (size_t)idx * HID + c];
        }
        float acc = 0.f;
        #pragma unroll
        for (int j = 0; j < NLVL; ++j) { acc += e[j]; s_pool2[j * HID + c] = acc; }
    }
    __syncthreads();

    // ---- stage 2: qk[qrow][c] = lvl[qrow>>2] . M[qrow&3][c][:] + Bf ; qb = lvl . vb + cb ----
    if (tid < 128) {
        const int c = tid;
        float acc[4][NLVL];
        #pragma unroll
        for (int g = 0; g < 4; ++g) {
            float bf = ws[WS_BF + g * 128 + c];
            #pragma unroll
            for (int qi = 0; qi < NLVL; ++qi) acc[g][qi] = bf;
        }
        const float4* M0 = (const float4*)(ws + WS_M + 0 * 16384 + c * 128);
        const float4* M1 = (const float4*)(ws + WS_M + 1 * 16384 + c * 128);
        const float4* M2 = (const float4*)(ws + WS_M + 2 * 16384 + c * 128);
        const float4* M3 = (const float4*)(ws + WS_M + 3 * 16384 + c * 128);
        const float4* lv4 = (const float4*)s_pool2;
        #pragma unroll 2
        for (int m = 0; m < 32; ++m) {
            float4 a0 = M0[m], a1 = M1[m], a2 = M2[m], a3 = M3[m];
            #pragma unroll
            for (int qi = 0; qi < NLVL; ++qi) {
                float4 l = lv4[qi * 32 + m];
                acc[0][qi] += a0.x * l.x + a0.y * l.y + a0.z * l.z + a0.w * l.w;
                acc[1][qi] += a1.x * l.x + a1.y * l.y + a1.z * l.z + a1.w * l.w;
                acc[2][qi] += a2.x * l.x + a2.y * l.y + a2.z * l.z + a2.w * l.w;
                acc[3][qi] += a3.x * l.x + a3.y * l.y + a3.z * l.z + a3.w * l.w;
            }
        }
        #pragma unroll
        for (int g = 0; g < 4; ++g)
            #pragma unroll
            for (int qi = 0; qi < NLVL; ++qi)
                s_pool1[(qi * 4 + g) * 128 + c] = acc[g][qi];
    } else if (tid < 128 + 28) {
        int qrow = tid - 128;
        int g = qrow & 3, L = qrow >> 2;
        const float* vb = ws + WS_VB + g * 128;
        const float* lv = s_pool2 + L * 128;
        float acc = ws[WS_CB + g];
        #pragma unroll 8
        for (int j = 0; j < 128; ++j) acc += lv[j] * vb[j];
        s_qb[qrow] = acc;
    }
    __syncthreads();

    // ---- stage 3: scores + sigmoid -> s_pool2 as [14][200] (lvl dead) ----
    for (int o = tid; o < 700; o += 512) {
        int hl = o / 50, gq = o % 50;
        int h = (hl >= 7) ? 1 : 0;
        int rA = h * 100 + gq, rB = rA + 50;
        const unsigned* eA = s_embu + rA * ESTR;
        const unsigned* eB = s_embu + rB * ESTR;
        const float4* k0 = (const float4*)(s_pool1 + (hl * 2) * 128);
        const float4* k1 = (const float4*)(s_pool1 + (hl * 2 + 1) * 128);
        float a0 = 0.f, a1 = 0.f, b0 = 0.f, b1 = 0.f;
        #pragma unroll 4
        for (int m = 0; m < 32; ++m) {
            uint2 ua = *(const uint2*)(eA + 2 * m);
            uint2 ub = *(const uint2*)(eB + 2 * m);
            float4 w0 = k0[m], w1 = k1[m];
            float x0 = bf_lo(ua.x), x1 = bf_hi(ua.x), x2 = bf_lo(ua.y), x3 = bf_hi(ua.y);
            float y0 = bf_lo(ub.x), y1 = bf_hi(ub.x), y2 = bf_lo(ub.y), y3 = bf_hi(ub.y);
            a0 += x0 * w0.x + x1 * w0.y + x2 * w0.z + x3 * w0.w;
            a1 += x0 * w1.x + x1 * w1.y + x2 * w1.z + x3 * w1.w;
            b0 += y0 * w0.x + y1 * w0.y + y2 * w0.z + y3 * w0.w;
            b1 += y0 * w1.x + y1 * w1.y + y2 * w1.z + y3 * w1.w;
        }
        float qb0 = s_qb[hl * 2], qb1 = s_qb[hl * 2 + 1];
        float* row = s_pool2 + hl * 200;
        *(float2*)(row + 2 * gq)       = make_float2(1.f / (1.f + __expf(-(a0 + qb0))),
                                                     1.f / (1.f + __expf(-(a1 + qb1))));
        *(float2*)(row + 2 * gq + 100) = make_float2(1.f / (1.f + __expf(-(b0 + qb0))),
                                                     1.f / (1.f + __expf(-(b1 + qb1))));
    }
    __syncthreads();

    // ---- stage 4: softmax over s2 per (h,l) row; inputs in (0,1): no max-sub needed ----
    const int wave = tid >> 6, lane = tid & 63;
    for (int r = wave; r < 14; r += 8) {
        float* row = s_pool2 + r * 200;
        float e0 = __expf(row[lane]);
        float e1 = __expf(row[lane + 64]);
        float e2 = __expf(row[lane + 128]);
        float e3 = (lane + 192 < 200) ? __expf(row[lane + 192]) : 0.f;
        float sum = e0 + e1 + e2 + e3;
        #pragma unroll
        for (int m = 1; m < 64; m <<= 1) sum += __shfl_xor(sum, m, 64);
        float inv = 1.f / sum;
        row[lane]       = e0 * inv;
        row[lane + 64]  = e1 * inv;
        row[lane + 128] = e2 * inv;
        if (lane + 192 < 200) row[lane + 192] = e3 * inv;
    }
    __syncthreads();

    // ---- stage 5: LP-pool (p=4) + mask + exp ----
    if (tid < 2 * SEQ) {
        int h = tid / SEQ, s2 = tid % SEQ;
        float ssum = 0.f;
        #pragma unroll
        for (int l = 0; l < NLVL; ++l) {
            float v = s_pool2[(h * NLVL + l) * 200 + s2];
            float v2 = v * v;
            ssum += v2 * v2;
        }
        float A = sqrtf(sqrtf(ssum));
        int m = item_seq[(size_t)b * SEQ + s2];
        s_A[tid] = (m > 0) ? __expf(A) : 0.f;
    }
    __syncthreads();

    // ---- stage 6: 2nd softmax denominators ----
    if (wave < 2) {
        const float* row = s_A + wave * SEQ;
        float sum = row[lane] + row[lane + 64] + row[lane + 128]
                  + ((lane + 192 < 200) ? row[lane + 192] : 0.f);
        #pragma unroll
        for (int m = 1; m < 64; m <<= 1) sum += __shfl_xor(sum, m, 64);
        if (lane == 0) s_inv[wave] = 1.f / sum;
    }
    __syncthreads();

    // ---- stage 7: weighted sum over s2 (4-way split), then combine ----
    {
        int c = tid & 127, qq = tid >> 7;
        int h = c >> 6;
        const float* wv = s_A + h * SEQ + qq * 50;
        const unsigned* eb = s_embu + (qq * 50) * ESTR + (c >> 1);
        float acc = 0.f;
        #pragma unroll 5
        for (int s = 0; s < 50; ++s) {
            unsigned u = eb[s * ESTR];
            acc += wv[s] * ((c & 1) ? bf_hi(u) : bf_lo(u));
        }
        s_pool1[tid] = acc;  // qk dead
    }
    __syncthreads();
    if (tid < HID) {
        int h = tid >> 6;
        float tot = (s_pool1[tid] + s_pool1[tid + 128] + s_pool1[tid + 256] + s_pool1[tid + 384]) * s_inv[h];
        out[(size_t)b * HID + tid] = tot;
    }
}

// ---- fallback (ws too small): round-3 proven monolithic fp32 kernel ----
__global__ __launch_bounds__(256) void mixer_fallback(
    const int* __restrict__ item_seq, const float* __restrict__ emb,
    const int* __restrict__ seq_len,
    const float* __restrict__ Wlq, const float* __restrict__ blq,
    const float* __restrict__ Wq,  const float* __restrict__ bq,
    const float* __restrict__ Wk,  const float* __restrict__ bk,
    float* __restrict__ out)
{
    const int b = blockIdx.x, tid = threadIdx.x;
    __shared__ unsigned s_embu[SEQ * 65];
    __shared__ float s_qk[28 * 128];
    __shared__ float s_qb[28];
    __shared__ float s_tmp[2800];
    __shared__ float s_A[400];
    __shared__ float s_red[256];
    __shared__ float s_inv[2];

    {
        const float4* src = (const float4*)(emb + (size_t)b * SEQ * HID);
        for (int i = tid; i < SEQ * 32; i += 256) {
            int row = i >> 5, j = i & 31;
            float4 v = src[i];
            unsigned* dst = s_embu + row * 65 + 2 * j;
            dst[0] = pack_bf(v.x, v.y);
            dst[1] = pack_bf(v.z, v.w);
        }
    }
    const int len = seq_len[b];
    if (tid < HID) {
        float acc = 0.f;
        for (int j = 0; j < NLVL; ++j) {
            int idx = len - (j + 1);
            if (idx < 0) idx = SEQ - 1;
            acc += emb[(size_t)b * SEQ * HID + (size_t)idx * HID + tid];
            s_tmp[j * HID + tid] = acc;
        }
    }
    __syncthreads();
    for (int t = tid; t < NLVL * HID; t += 256) {
        int l = t >> 7, c = t & 127;
        const float* x = s_tmp + l * HID;
        float acc = blq[c];
        #pragma unroll 8
        for (int k = 0; k < HID; ++k) acc += x[k] * Wlq[c * HID + k];
        s_tmp[896 + t] = acc;
    }
    __syncthreads();
    for (int t = tid; t < NLVL * HID; t += 256) {
        int l = t >> 7, c = t & 127;
        const float* x = s_tmp + 896 + l * HID;
        float acc = bq[c];
        #pragma unroll 8
        for (int k = 0; k < HID; ++k) acc += x[k] * Wq[c * HID + k];
        s_tmp[t] = acc;
    }
    __syncthreads();
    for (int o = tid; o < 28 * 128; o += 256) {
        int qrow = o >> 7, c = o & 127;
        int hl = qrow >> 1, par = qrow & 1;
        const float* qv = s_tmp + hl * 64;
        float acc = 0.f;
        #pragma unroll 8
        for (int d2 = 0; d2 < 64; ++d2) acc += qv[d2] * Wk[(par * 64 + d2) * HID + c];
        s_qk[qrow * 128 + c] = acc;
    }
    if (tid < 28) {
        int hl = tid >> 1, par = tid & 1;
        float acc = 0.f;
        for (int d2 = 0; d2 < 64; ++d2) acc += s_tmp[hl * 64 + d2] * bk[par * 64 + d2];
        s_qb[tid] = acc;
    }
    __syncthreads();
    for (int o = tid; o < 700; o += 256) {
        int hl = o / 50, g = o % 50;
        int h = (hl >= 7) ? 1 : 0;
        int rA = h * 100 + g, rB = rA + 50;
        const unsigned* eA = s_embu + rA * 65;
        const unsigned* eB = s_embu + rB * 65;
        const float* k0 = s_qk + (hl * 2) * 128;
        const float* k1 = s_qk + (hl * 2 + 1) * 128;
        float a0 = 0.f, a1 = 0.f, c0a = 0.f, c1a = 0.f;
        #pragma unroll 4
        for (int kk = 0; kk < 64; ++kk) {
            unsigned uA = eA[kk], uB = eB[kk];
            float2 w0 = *(const float2*)(k0 + 2 * kk);
            float2 w1 = *(const float2*)(k1 + 2 * kk);
            float alo = bf_lo(uA), ahi = bf_hi(uA);
            float blo = bf_lo(uB), bhi = bf_hi(uB);
            a0 += alo * w0.x + ahi * w0.y;  a1 += alo * w1.x + ahi * w1.y;
            c0a += blo * w0.x + bhi * w0.y; c1a += blo * w1.x + bhi * w1.y;
        }
        float qb0 = s_qb[hl * 2], qb1 = s_qb[hl * 2 + 1];
        float* row = s_tmp + hl * 200;
        row[2 * g]       = 1.f / (1.f + __expf(-(a0 + qb0)));
        row[2 * g + 1]   = 1.f / (1.f + __expf(-(a1 + qb1)));
        row[2 * g + 100] = 1.f / (1.f + __expf(-(c0a + qb0)));
        row[2 * g + 101] = 1.f / (1.f + __expf(-(c1a + qb1)));
    }
    __syncthreads();
    const int wave = tid >> 6, lane = tid & 63;
    for (int r = wave; r < 14; r += 4) {
        float* row = s_tmp + r * 200;
        float e0 = __expf(row[lane]), e1 = __expf(row[lane + 64]);
        float e2 = __expf(row[lane + 128]);
        float e3 = (lane + 192 < 200) ? __expf(row[lane + 192]) : 0.f;
        float sum = e0 + e1 + e2 + e3;
        #pragma unroll
        for (int m = 1; m < 64; m <<= 1) sum += __shfl_xor(sum, m, 64);
        float inv = 1.f / sum;
        row[lane] = e0 * inv; row[lane + 64] = e1 * inv; row[lane + 128] = e2 * inv;
        if (lane + 192 < 200) row[lane + 192] = e3 * inv;
    }
    __syncthreads();
    for (int o = tid; o < 2 * SEQ; o += 256) {
        int h = o / SEQ, s2 = o % SEQ;
        float ssum = 0.f;
        #pragma unroll
        for (int l = 0; l < NLVL; ++l) {
            float v = s_tmp[(h * NLVL + l) * 200 + s2];
            float v2 = v * v; ssum += v2 * v2;
        }
        float A = sqrtf(sqrtf(ssum));
        s_A[o] = (item_seq[(size_t)b * SEQ + s2] > 0) ? __expf(A) : 0.f;
    }
    __syncthreads();
    if (wave < 2) {
        const float* row = s_A + wave * SEQ;
        float sum = row[lane] + row[lane + 64] + row[lane + 128]
                  + ((lane + 192 < 200) ? row[lane + 192] : 0.f);
        #pragma unroll
        for (int m = 1; m < 64; m <<= 1) sum += __shfl_xor(sum, m, 64);
        if (lane == 0) s_inv[wave] = 1.f / sum;
    }
    __syncthreads();
    {
        int c = tid & 127, halfb = tid >> 7;
        int h = c >> 6;
        const float* wv = s_A + h * SEQ + halfb * 100;
        float acc = 0.f;
        #pragma unroll 4
        for (int s2 = 0; s2 < 100; ++s2) {
            unsigned u = s_embu[(halfb * 100 + s2) * 65 + (c >> 1)];
            acc += wv[s2] * ((c & 1) ? bf_hi(u) : bf_lo(u));
        }
        s_red[tid] = acc;
    }
    __syncthreads();
    if (tid < HID) {
        int h = tid >> 6;
        out[(size_t)b * HID + tid] = (s_red[tid] + s_red[tid + 128]) * s_inv[h];
    }
}

extern "C" void kernel_launch(void* const* d_in, const int* in_sizes, int n_in,
                              void* d_out, int out_size, void* d_ws, size_t ws_size,
                              hipStream_t stream) {
    const int* item_seq = (const int*)d_in[0];
    const float* emb    = (const float*)d_in[1];
    const int* seq_len  = (const int*)d_in[2];
    const float* Wlq    = (const float*)d_in[3];
    const float* blq    = (const float*)d_in[4];
    const float* Wq     = (const float*)d_in[5];
    const float* bq     = (const float*)d_in[6];
    const float* Wk     = (const float*)d_in[7];
    const float* bk     = (const float*)d_in[8];
    float* out          = (float*)d_out;
    const int B = in_sizes[2];  // 2048

    if (ws_size >= (size_t)WS_WORDS * 4) {
        float* ws = (float*)d_ws;
        precomp0<<<64, 256, 0, stream>>>(Wlq, blq, Wq, bq, ws);
        precomp1<<<261, 256, 0, stream>>>(Wk, bk, ws);
        mixer_main<<<B, 512, 0, stream>>>(item_seq, emb, seq_len, ws, out);
    } else {
        mixer_fallback<<<B, 256, 0, stream>>>(item_seq, emb, seq_len, Wlq, blq, Wq, bq, Wk, bk, out);
    }
}

// Round 5
// 392.213 us; speedup vs baseline: 1.5849x; 1.1549x over previous
//
#include <hip/hip_runtime.h>
#include <hip/hip_bf16.h>

// B=2048, S=200, H=128, nh=2, L=7, d=64. Inputs/outputs fp32 (verified round 3/4).
#define SEQ 200
#define HID 128
#define NLVL 7
#define ESTR 66  // LDS emb row stride (uints); even => 8B-aligned rows

// ws word offsets
#define WS_M16_W 0        // M16[4][128][128] bf16 = 65536 bf16 = 32768 words
#define WS_BF    32768    // Bf[4][128] fp32
#define WS_VB    33280    // vb[4][128] fp32
#define WS_CB    33792    // cb[4]
#define WS_WC    33796    // Wcomb[128][128] fp32 (staging)
#define WS_BC    50180    // bcomb[128]
#define WS_WORDS 50308

typedef __attribute__((ext_vector_type(8))) short short8;   // 8 bf16 (4 VGPRs)
typedef __attribute__((ext_vector_type(4))) float f32x4;    // MFMA acc

__device__ __forceinline__ float bf_lo(unsigned u) { return __uint_as_float(u << 16); }
__device__ __forceinline__ float bf_hi(unsigned u) { return __uint_as_float(u & 0xffff0000u); }
__device__ __forceinline__ unsigned short bf_bits(float f) {
    __hip_bfloat16 h = __float2bfloat16(f);
    return *reinterpret_cast<unsigned short*>(&h);
}
__device__ __forceinline__ unsigned pack_bf(float a, float b) {
    return (unsigned)bf_bits(a) | ((unsigned)bf_bits(b) << 16);
}

// ---- precompute 0: Wcomb = Wq @ Wlq, bcomb = Wq @ b_lq + bq ----
__global__ __launch_bounds__(256) void precomp0(
    const float* __restrict__ Wlq, const float* __restrict__ blq,
    const float* __restrict__ Wq,  const float* __restrict__ bq,
    float* __restrict__ ws)
{
    int id = blockIdx.x * 256 + threadIdx.x;  // [0, 16384)
    int r = id >> 7, j = id & 127;
    float acc = 0.f;
    #pragma unroll 8
    for (int c = 0; c < 128; ++c) acc += Wq[r * 128 + c] * Wlq[c * 128 + j];
    ws[WS_WC + id] = acc;
    if (id < 128) {
        float b = bq[id];
        #pragma unroll 8
        for (int c = 0; c < 128; ++c) b += Wq[id * 128 + c] * blq[c];
        ws[WS_BC + id] = b;
    }
}

// ---- precompute 1: M16[g][c][j] (bf16) = sum_d Wcomb[u*64+d][j]*Wk[par*64+d][c]; Bf, vb, cb ----
__global__ __launch_bounds__(256) void precomp1(
    const float* __restrict__ Wk, const float* __restrict__ bk, float* __restrict__ ws)
{
    int gid = blockIdx.x * 256 + threadIdx.x;
    if (gid < 65536) {
        int j = gid & 127, c = (gid >> 7) & 127, g = gid >> 14;
        int u = g >> 1, par = g & 1;
        const float* wc = ws + WS_WC + u * 64 * 128 + j;
        const float* wk = Wk + par * 64 * 128 + c;
        float acc = 0.f;
        #pragma unroll 8
        for (int d = 0; d < 64; ++d) acc += wc[d * 128] * wk[d * 128];
        ((__hip_bfloat16*)ws)[gid] = __float2bfloat16(acc);   // M16 at word 0
    } else if (gid < 66048) {
        int t = gid - 65536, c = t & 127, g = t >> 7;
        int u = g >> 1, par = g & 1;
        float acc = 0.f;
        #pragma unroll 8
        for (int d = 0; d < 64; ++d)
            acc += ws[WS_BC + u * 64 + d] * Wk[(par * 64 + d) * 128 + c];
        ws[WS_BF + t] = acc;
    } else if (gid < 66560) {
        int t = gid - 66048, j = t & 127, g = t >> 7;
        int u = g >> 1, par = g & 1;
        float acc = 0.f;
        #pragma unroll 8
        for (int d = 0; d < 64; ++d)
            acc += ws[WS_WC + (u * 64 + d) * 128 + j] * bk[par * 64 + d];
        ws[WS_VB + t] = acc;
    } else if (gid < 66564) {
        int g = gid - 66560, u = g >> 1, par = g & 1;
        float acc = 0.f;
        for (int d = 0; d < 64; ++d)
            acc += ws[WS_BC + u * 64 + d] * bk[par * 64 + d];
        ws[WS_CB + g] = acc;
    }
}

// ---- main kernel: one block per batch, 512 threads ----
__global__ __launch_bounds__(512, 4) void mixer_main(
    const int* __restrict__ item_seq,
    const float* __restrict__ emb,
    const int* __restrict__ seq_len,
    const float* __restrict__ ws,
    float* __restrict__ out)
{
    const int b   = blockIdx.x;
    const int tid = threadIdx.x;

    __shared__ __align__(16) unsigned s_embu[SEQ * ESTR];  // 52800 B, packed bf16
    __shared__ __align__(16) float    s_qk[28 * 128];      // qk fp32; later partial sums (14336 B)
    __shared__ float                  s_qb[28];
    __shared__ __align__(16) float    s_pool2[2800];       // lvl fp32 [0..895] + lvl16 bf16 @ [1024..2112); then scores [14][200]
    __shared__ float                  s_A[2 * SEQ];
    __shared__ float                  s_inv[2];
    // total 80,056 B -> 2 blocks/CU

    // ---- stage 0: emb -> LDS packed bf16 (coalesced float4) ----
    {
        const float4* src = (const float4*)(emb + (size_t)b * SEQ * HID);
        for (int i = tid; i < SEQ * 32; i += 512) {
            int row = i >> 5, j = i & 31;
            float4 v = src[i];
            unsigned* dst = s_embu + row * ESTR + 2 * j;
            dst[0] = pack_bf(v.x, v.y);
            dst[1] = pack_bf(v.z, v.w);
        }
    }
    // ---- stage 1: level gather + cumsum -> lvl fp32 in s_pool2[0..895] + lvl16 bf16 [7][136] ----
    if (tid < HID) {
        const int len = seq_len[b];
        const int c = tid;
        float e[NLVL];
        #pragma unroll
        for (int j = 0; j < NLVL; ++j) {
            int idx = len - (j + 1);
            if (idx < 0) idx = SEQ - 1;  // torch clamp(-1) + wrap
            e[j] = emb[(size_t)b * SEQ * HID + (size_t)idx * HID + c];
        }
        short* lvl16 = (short*)(s_pool2 + 1024);
        float acc = 0.f;
        #pragma unroll
        for (int j = 0; j < NLVL; ++j) {
            acc += e[j];
            s_pool2[j * HID + c] = acc;
            lvl16[j * 136 + c] = (short)bf_bits(acc);
        }
    }
    __syncthreads();

    // ---- stage 2: qk = lvl @ M^T via MFMA 16x16x32 bf16; D layout col=lane&15,row=quad*4+reg ----
    {
        const int w = tid >> 6, l = tid & 63;
        const int g = w >> 1, halfm = w & 1;
        const int mrow = l & 15, quad = l >> 4;
        const short* lvl16 = (const short*)(s_pool2 + 1024);
        short8 bfrag[4];
        #pragma unroll
        for (int k = 0; k < 4; ++k)
            bfrag[k] = *(const short8*)(lvl16 + mrow * 136 + k * 32 + quad * 8);
        const short* M16 = (const short*)ws;  // [4][128][128] bf16
        #pragma unroll
        for (int mt = 0; mt < 4; ++mt) {
            int mtile = halfm * 4 + mt;
            int cbase = mtile * 16 + quad * 4;
            f32x4 acc;
            #pragma unroll
            for (int r = 0; r < 4; ++r) acc[r] = ws[WS_BF + g * 128 + cbase + r];
            const short* Ab = M16 + (g * 128 + mtile * 16 + mrow) * 128;
            #pragma unroll
            for (int k = 0; k < 4; ++k) {
                short8 afrag = *(const short8*)(Ab + k * 32 + quad * 8);
                acc = __builtin_amdgcn_mfma_f32_16x16x32_bf16(afrag, bfrag[k], acc, 0, 0, 0);
            }
            if (mrow < NLVL)  // D rows n>=7 are junk (lvl16 rows 7..15 uninitialized) - never written
                *(f32x4*)(s_qk + (mrow * 4 + g) * 128 + cbase) = acc;
        }
        if (tid < 28) {  // qb[qrow] = lvl . vb[g] + cb[g]
            int qrow = tid, gg = qrow & 3, L = qrow >> 2;
            const float* vb = ws + WS_VB + gg * 128;
            const float* lv = s_pool2 + L * 128;
            float acc = ws[WS_CB + gg];
            #pragma unroll 8
            for (int j = 0; j < 128; ++j) acc += lv[j] * vb[j];
            s_qb[qrow] = acc;
        }
    }
    __syncthreads();

    // ---- stage 3: scores + sigmoid -> s_pool2 as [14][200] (lvl dead) ----
    for (int o = tid; o < 700; o += 512) {
        int hl = o / 50, gq = o % 50;
        int h = (hl >= 7) ? 1 : 0;
        int rA = h * 100 + gq, rB = rA + 50;
        const unsigned* eA = s_embu + rA * ESTR;
        const unsigned* eB = s_embu + rB * ESTR;
        const float4* k0 = (const float4*)(s_qk + (hl * 2) * 128);
        const float4* k1 = (const float4*)(s_qk + (hl * 2 + 1) * 128);
        float a0 = 0.f, a1 = 0.f, b0 = 0.f, b1 = 0.f;
        #pragma unroll 4
        for (int m = 0; m < 32; ++m) {
            uint2 ua = *(const uint2*)(eA + 2 * m);
            uint2 ub = *(const uint2*)(eB + 2 * m);
            float4 w0 = k0[m], w1 = k1[m];
            float x0 = bf_lo(ua.x), x1 = bf_hi(ua.x), x2 = bf_lo(ua.y), x3 = bf_hi(ua.y);
            float y0 = bf_lo(ub.x), y1 = bf_hi(ub.x), y2 = bf_lo(ub.y), y3 = bf_hi(ub.y);
            a0 += x0 * w0.x + x1 * w0.y + x2 * w0.z + x3 * w0.w;
            a1 += x0 * w1.x + x1 * w1.y + x2 * w1.z + x3 * w1.w;
            b0 += y0 * w0.x + y1 * w0.y + y2 * w0.z + y3 * w0.w;
            b1 += y0 * w1.x + y1 * w1.y + y2 * w1.z + y3 * w1.w;
        }
        float qb0 = s_qb[hl * 2], qb1 = s_qb[hl * 2 + 1];
        float* row = s_pool2 + hl * 200;
        *(float2*)(row + 2 * gq)       = make_float2(1.f / (1.f + __expf(-(a0 + qb0))),
                                                     1.f / (1.f + __expf(-(a1 + qb1))));
        *(float2*)(row + 2 * gq + 100) = make_float2(1.f / (1.f + __expf(-(b0 + qb0))),
                                                     1.f / (1.f + __expf(-(b1 + qb1))));
    }
    __syncthreads();

    // ---- stage 4: softmax over s2 per (h,l) row; inputs in (0,1): no max-sub needed ----
    const int wave = tid >> 6, lane = tid & 63;
    for (int r = wave; r < 14; r += 8) {
        float* row = s_pool2 + r * 200;
        float e0 = __expf(row[lane]);
        float e1 = __expf(row[lane + 64]);
        float e2 = __expf(row[lane + 128]);
        float e3 = (lane + 192 < 200) ? __expf(row[lane + 192]) : 0.f;
        float sum = e0 + e1 + e2 + e3;
        #pragma unroll
        for (int m = 1; m < 64; m <<= 1) sum += __shfl_xor(sum, m, 64);
        float inv = 1.f / sum;
        row[lane]       = e0 * inv;
        row[lane + 64]  = e1 * inv;
        row[lane + 128] = e2 * inv;
        if (lane + 192 < 200) row[lane + 192] = e3 * inv;
    }
    __syncthreads();

    // ---- stage 5: LP-pool (p=4) + mask + exp ----
    if (tid < 2 * SEQ) {
        int h = tid / SEQ, s2 = tid % SEQ;
        float ssum = 0.f;
        #pragma unroll
        for (int l = 0; l < NLVL; ++l) {
            float v = s_pool2[(h * NLVL + l) * 200 + s2];
            float v2 = v * v;
            ssum += v2 * v2;
        }
        float A = sqrtf(sqrtf(ssum));
        int m = item_seq[(size_t)b * SEQ + s2];
        s_A[tid] = (m > 0) ? __expf(A) : 0.f;
    }
    __syncthreads();

    // ---- stage 6: 2nd softmax denominators ----
    if (wave < 2) {
        const float* row = s_A + wave * SEQ;
        float sum = row[lane] + row[lane + 64] + row[lane + 128]
                  + ((lane + 192 < 200) ? row[lane + 192] : 0.f);
        #pragma unroll
        for (int m = 1; m < 64; m <<= 1) sum += __shfl_xor(sum, m, 64);
        if (lane == 0) s_inv[wave] = 1.f / sum;
    }
    __syncthreads();

    // ---- stage 7: weighted sum over s2 (4-way split), then combine ----
    {
        int c = tid & 127, qq = tid >> 7;
        int h = c >> 6;
        const float* wv = s_A + h * SEQ + qq * 50;
        const unsigned* eb = s_embu + (qq * 50) * ESTR + (c >> 1);
        float acc = 0.f;
        #pragma unroll 5
        for (int s = 0; s < 50; ++s) {
            unsigned u = eb[s * ESTR];
            acc += wv[s] * ((c & 1) ? bf_hi(u) : bf_lo(u));
        }
        s_qk[tid] = acc;  // qk dead
    }
    __syncthreads();
    if (tid < HID) {
        int h = tid >> 6;
        float tot = (s_qk[tid] + s_qk[tid + 128] + s_qk[tid + 256] + s_qk[tid + 384]) * s_inv[h];
        out[(size_t)b * HID + tid] = tot;
    }
}

// ---- fallback (ws too small): round-3 proven monolithic fp32 kernel ----
__global__ __launch_bounds__(256) void mixer_fallback(
    const int* __restrict__ item_seq, const float* __restrict__ emb,
    const int* __restrict__ seq_len,
    const float* __restrict__ Wlq, const float* __restrict__ blq,
    const float* __restrict__ Wq,  const float* __restrict__ bq,
    const float* __restrict__ Wk,  const float* __restrict__ bk,
    float* __restrict__ out)
{
    const int b = blockIdx.x, tid = threadIdx.x;
    __shared__ unsigned s_embu[SEQ * 65];
    __shared__ float s_qk[28 * 128];
    __shared__ float s_qb[28];
    __shared__ float s_tmp[2800];
    __shared__ float s_A[400];
    __shared__ float s_red[256];
    __shared__ float s_inv[2];

    {
        const float4* src = (const float4*)(emb + (size_t)b * SEQ * HID);
        for (int i = tid; i < SEQ * 32; i += 256) {
            int row = i >> 5, j = i & 31;
            float4 v = src[i];
            unsigned* dst = s_embu + row * 65 + 2 * j;
            dst[0] = pack_bf(v.x, v.y);
            dst[1] = pack_bf(v.z, v.w);
        }
    }
    const int len = seq_len[b];
    if (tid < HID) {
        float acc = 0.f;
        for (int j = 0; j < NLVL; ++j) {
            int idx = len - (j + 1);
            if (idx < 0) idx = SEQ - 1;
            acc += emb[(size_t)b * SEQ * HID + (size_t)idx * HID + tid];
            s_tmp[j * HID + tid] = acc;
        }
    }
    __syncthreads();
    for (int t = tid; t < NLVL * HID; t += 256) {
        int l = t >> 7, c = t & 127;
        const float* x = s_tmp + l * HID;
        float acc = blq[c];
        #pragma unroll 8
        for (int k = 0; k < HID; ++k) acc += x[k] * Wlq[c * HID + k];
        s_tmp[896 + t] = acc;
    }
    __syncthreads();
    for (int t = tid; t < NLVL * HID; t += 256) {
        int l = t >> 7, c = t & 127;
        const float* x = s_tmp + 896 + l * HID;
        float acc = bq[c];
        #pragma unroll 8
        for (int k = 0; k < HID; ++k) acc += x[k] * Wq[c * HID + k];
        s_tmp[t] = acc;
    }
    __syncthreads();
    for (int o = tid; o < 28 * 128; o += 256) {
        int qrow = o >> 7, c = o & 127;
        int hl = qrow >> 1, par = qrow & 1;
        const float* qv = s_tmp + hl * 64;
        float acc = 0.f;
        #pragma unroll 8
        for (int d2 = 0; d2 < 64; ++d2) acc += qv[d2] * Wk[(par * 64 + d2) * HID + c];
        s_qk[qrow * 128 + c] = acc;
    }
    if (tid < 28) {
        int hl = tid >> 1, par = tid & 1;
        float acc = 0.f;
        for (int d2 = 0; d2 < 64; ++d2) acc += s_tmp[hl * 64 + d2] * bk[par * 64 + d2];
        s_qb[tid] = acc;
    }
    __syncthreads();
    for (int o = tid; o < 700; o += 256) {
        int hl = o / 50, g = o % 50;
        int h = (hl >= 7) ? 1 : 0;
        int rA = h * 100 + g, rB = rA + 50;
        const unsigned* eA = s_embu + rA * 65;
        const unsigned* eB = s_embu + rB * 65;
        const float* k0 = s_qk + (hl * 2) * 128;
        const float* k1 = s_qk + (hl * 2 + 1) * 128;
        float a0 = 0.f, a1 = 0.f, c0a = 0.f, c1a = 0.f;
        #pragma unroll 4
        for (int kk = 0; kk < 64; ++kk) {
            unsigned uA = eA[kk], uB = eB[kk];
            float2 w0 = *(const float2*)(k0 + 2 * kk);
            float2 w1 = *(const float2*)(k1 + 2 * kk);
            float alo = bf_lo(uA), ahi = bf_hi(uA);
            float blo = bf_lo(uB), bhi = bf_hi(uB);
            a0 += alo * w0.x + ahi * w0.y;  a1 += alo * w1.x + ahi * w1.y;
            c0a += blo * w0.x + bhi * w0.y; c1a += blo * w1.x + bhi * w1.y;
        }
        float qb0 = s_qb[hl * 2], qb1 = s_qb[hl * 2 + 1];
        float* row = s_tmp + hl * 200;
        row[2 * g]       = 1.f / (1.f + __expf(-(a0 + qb0)));
        row[2 * g + 1]   = 1.f / (1.f + __expf(-(a1 + qb1)));
        row[2 * g + 100] = 1.f / (1.f + __expf(-(c0a + qb0)));
        row[2 * g + 101] = 1.f / (1.f + __expf(-(c1a + qb1)));
    }
    __syncthreads();
    const int wave = tid >> 6, lane = tid & 63;
    for (int r = wave; r < 14; r += 4) {
        float* row = s_tmp + r * 200;
        float e0 = __expf(row[lane]), e1 = __expf(row[lane + 64]);
        float e2 = __expf(row[lane + 128]);
        float e3 = (lane + 192 < 200) ? __expf(row[lane + 192]) : 0.f;
        float sum = e0 + e1 + e2 + e3;
        #pragma unroll
        for (int m = 1; m < 64; m <<= 1) sum += __shfl_xor(sum, m, 64);
        float inv = 1.f / sum;
        row[lane] = e0 * inv; row[lane + 64] = e1 * inv; row[lane + 128] = e2 * inv;
        if (lane + 192 < 200) row[lane + 192] = e3 * inv;
    }
    __syncthreads();
    for (int o = tid; o < 2 * SEQ; o += 256) {
        int h = o / SEQ, s2 = o % SEQ;
        float ssum = 0.f;
        #pragma unroll
        for (int l = 0; l < NLVL; ++l) {
            float v = s_tmp[(h * NLVL + l) * 200 + s2];
            float v2 = v * v; ssum += v2 * v2;
        }
        float A = sqrtf(sqrtf(ssum));
        s_A[o] = (item_seq[(size_t)b * SEQ + s2] > 0) ? __expf(A) : 0.f;
    }
    __syncthreads();
    if (wave < 2) {
        const float* row = s_A + wave * SEQ;
        float sum = row[lane] + row[lane + 64] + row[lane + 128]
                  + ((lane + 192 < 200) ? row[lane + 192] : 0.f);
        #pragma unroll
        for (int m = 1; m < 64; m <<= 1) sum += __shfl_xor(sum, m, 64);
        if (lane == 0) s_inv[wave] = 1.f / sum;
    }
    __syncthreads();
    {
        int c = tid & 127, halfb = tid >> 7;
        int h = c >> 6;
        const float* wv = s_A + h * SEQ + halfb * 100;
        float acc = 0.f;
        #pragma unroll 4
        for (int s2 = 0; s2 < 100; ++s2) {
            unsigned u = s_embu[(halfb * 100 + s2) * 65 + (c >> 1)];
            acc += wv[s2] * ((c & 1) ? bf_hi(u) : bf_lo(u));
        }
        s_red[tid] = acc;
    }
    __syncthreads();
    if (tid < HID) {
        int h = tid >> 6;
        out[(size_t)b * HID + tid] = (s_red[tid] + s_red[tid + 128]) * s_inv[h];
    }
}

extern "C" void kernel_launch(void* const* d_in, const int* in_sizes, int n_in,
                              void* d_out, int out_size, void* d_ws, size_t ws_size,
                              hipStream_t stream) {
    const int* item_seq = (const int*)d_in[0];
    const float* emb    = (const float*)d_in[1];
    const int* seq_len  = (const int*)d_in[2];
    const float* Wlq    = (const float*)d_in[3];
    const float* blq    = (const float*)d_in[4];
    const float* Wq     = (const float*)d_in[5];
    const float* bq     = (const float*)d_in[6];
    const float* Wk     = (const float*)d_in[7];
    const float* bk     = (const float*)d_in[8];
    float* out          = (float*)d_out;
    const int B = in_sizes[2];  // 2048

    if (ws_size >= (size_t)WS_WORDS * 4) {
        float* ws = (float*)d_ws;
        precomp0<<<64, 256, 0, stream>>>(Wlq, blq, Wq, bq, ws);
        precomp1<<<261, 256, 0, stream>>>(Wk, bk, ws);
        mixer_main<<<B, 512, 0, stream>>>(item_seq, emb, seq_len, ws, out);
    } else {
        mixer_fallback<<<B, 256, 0, stream>>>(item_seq, emb, seq_len, Wlq, blq, Wq, bq, Wk, bk, out);
    }
}